// Round 9
// baseline (603.586 us; speedup 1.0000x reference)
//
#include <hip/hip_runtime.h>

typedef float f32x2 __attribute__((ext_vector_type(2)));
typedef float f32x4 __attribute__((ext_vector_type(4)));
typedef _Float16 h16;
typedef h16 h16x2 __attribute__((ext_vector_type(2)));
typedef int  int4v __attribute__((ext_vector_type(4)));

#define BB 256
#define TT 1024
#define HH 128
#define CC 2

// 2*log2(e): weights/bias pre-scaled so tanh needs no argument scaling.
#define LOG2E2 2.885390081777927f

// tanh(u) = 1 - 2/(exp2(u2)+1), u2 = 2*log2e*u (scale folded into weights).
__device__ __forceinline__ float ftanh2(float u2) {
    float e = __builtin_amdgcn_exp2f(u2);
    float r = __builtin_amdgcn_rcpf(e + 1.0f);
    return fmaf(-2.0f, r, 1.0f);
}

__device__ __forceinline__ float bcast(float v, int j) {
    return __int_as_float(__builtin_amdgcn_readlane(__float_as_int(v), j));
}
__device__ __forceinline__ int bcasti(int v, int j) {
    return __builtin_amdgcn_readlane(v, j);
}

#define DPP_ADD(v, ctrl)                                                     \
    ((v) + __int_as_float(__builtin_amdgcn_mov_dpp(                          \
         __float_as_int(v), (ctrl), 0xF, 0xF, true)))

// 2-term f16 dot with f32 accumulate; hedged fallback if builtin missing.
__device__ __forceinline__ float dot2(int w2, int h2, float acc) {
#if __has_builtin(__builtin_amdgcn_fdot2)
    h16x2 a = __builtin_bit_cast(h16x2, w2);
    h16x2 b = __builtin_bit_cast(h16x2, h2);
    return __builtin_amdgcn_fdot2(a, b, acc, false);
#else
    h16x2 a = __builtin_bit_cast(h16x2, w2);
    h16x2 b = __builtin_bit_cast(h16x2, h2);
    acc = fmaf((float)a.x, (float)b.x, acc);
    acc = fmaf((float)a.y, (float)b.y, acc);
    return acc;
#endif
}

// ---- prep: pack W_hh * 2log2e into f16 pairs (RTN) in workspace ----
// layout: ushort2-as-uint [row 0..127][k-pair 0..63], row-major.
__global__ void pack_w(const float* __restrict__ Whh, unsigned* __restrict__ wp) {
    int i = blockIdx.x * 256 + threadIdx.x;          // 0..8191 dwords
    float a = Whh[2 * i]     * LOG2E2;
    float b = Whh[2 * i + 1] * LOG2E2;
    h16 ha = (h16)a, hb = (h16)b;                    // RTN casts
    unsigned lo = (unsigned)__builtin_bit_cast(unsigned short, ha);
    unsigned hi = (unsigned)__builtin_bit_cast(unsigned short, hb);
    wp[i] = lo | (hi << 16);
}

// ---- main: ONE wave per batch. Zero LDS / zero barrier in the recurrence.
// R5/R6 lesson: step time = per-wave issue + ~550-780cyc barrier/LDS chain
// (grows with wave count; occupancy can't hide it - waves stall together).
// So: remove the chain entirely; cut issue with v_dot2_f32_f16 (1 readlane
// feeds 2 k's; 1 dot2 = 2 FMAs). h stays f32 in the recurrence; only the
// dot operand is f16-quantized per step (error doesn't compound as state).
__global__ __launch_bounds__(64, 1) void rnn_kernel(
    const float* __restrict__ x, const float* __restrict__ W_ih,
    const unsigned* __restrict__ wp, const float* __restrict__ b_ih,
    const float* __restrict__ b_hh, const float* __restrict__ W_fc,
    const float* __restrict__ b_fc, float* __restrict__ out)
{
    const int b = blockIdx.x;     // 0..255
    const int l = threadIdx.x;    // 0..63

    __shared__ float xs[TT + 4];  // input sequence (+pad for prefetch)

    // preload x row (64 lanes x 4 x f32x4, coalesced)
    {
        const f32x4* xr = (const f32x4*)(x + (size_t)b * TT);
        f32x4* xd = (f32x4*)xs;
        #pragma unroll
        for (int i = 0; i < 4; ++i) xd[i * 64 + l] = xr[i * 64 + l];
    }
    if (l < 4) xs[TT + l] = 0.f;

    // per-lane weights: rows l and l+64, f16-pair packed: 64 dwords each.
    // Compiler may keep some and refetch the rest from L1 per step - R5
    // proved refetch is latency-hidden; loads are independent of hn.
    int wA2[64], wB2[64];
    {
        const int4v* ra = (const int4v*)(wp + (size_t)l * 64);
        const int4v* rb = (const int4v*)(wp + (size_t)(l + 64) * 64);
        #pragma unroll
        for (int j = 0; j < 16; ++j) {
            int4v va = ra[j], vb = rb[j];
            wA2[4*j+0] = va.x; wA2[4*j+1] = va.y; wA2[4*j+2] = va.z; wA2[4*j+3] = va.w;
            wB2[4*j+0] = vb.x; wB2[4*j+1] = vb.y; wB2[4*j+2] = vb.z; wB2[4*j+3] = vb.w;
        }
    }

    const float wihA  = W_ih[l]      * LOG2E2;
    const float wihB  = W_ih[l + 64] * LOG2E2;
    const float biasA = (b_ih[l]      + b_hh[l])      * LOG2E2;
    const float biasB = (b_ih[l + 64] + b_hh[l + 64]) * LOG2E2;
    const float wf0A = W_fc[l],      wf0B = W_fc[l + 64];
    const float wf1A = W_fc[HH + l], wf1B = W_fc[HH + l + 64];
    const float bf0 = b_fc[0], bf1 = b_fc[1];

    float hnA = 0.f, hnB = 0.f;   // h_t[l], h_t[l+64] (f32 state)
    float* o = out + (size_t)b * TT * CC;

    __syncthreads();              // xs visible (one-time)
    float xcur = xs[0];

    #pragma unroll 2
    for (int t = 0; t < TT; ++t) {
        // ---- pack h to f16 pairs: lane 2j ends with pack(h[2j], h[2j+1]).
        // DPP xor1 brings the odd neighbor; cvt_pkrtz packs (RTZ, ~1e-3 rel).
        float swA = __int_as_float(__builtin_amdgcn_mov_dpp(
            __float_as_int(hnA), 0xB1, 0xF, 0xF, true));
        float swB = __int_as_float(__builtin_amdgcn_mov_dpp(
            __float_as_int(hnB), 0xB1, 0xF, 0xF, true));
        int pkA = __builtin_bit_cast(int, __builtin_amdgcn_cvt_pkrtz(hnA, swA));
        int pkB = __builtin_bit_cast(int, __builtin_amdgcn_cvt_pkrtz(hnB, swB));

        // ---- matvec: rows l, l+64 over full K=128.
        // j-th k-pair: h-pair = readlane(pkA/pkB, 2j) (SGPR, uniform);
        // 64 RL + 128 dot2 total. 4 accumulators for ILP.
        float aA0 = 0.f, aA1 = 0.f, aB0 = 0.f, aB1 = 0.f;
        #pragma unroll
        for (int j = 0; j < 32; j += 2) {
            int h0 = bcasti(pkA, 2 * j);
            int h1 = bcasti(pkA, 2 * j + 2);
            aA0 = dot2(wA2[j],     h0, aA0);
            aB0 = dot2(wB2[j],     h0, aB0);
            aA1 = dot2(wA2[j + 1], h1, aA1);
            aB1 = dot2(wB2[j + 1], h1, aB1);
        }
        #pragma unroll
        for (int j = 0; j < 32; j += 2) {
            int h0 = bcasti(pkB, 2 * j);
            int h1 = bcasti(pkB, 2 * j + 2);
            aA0 = dot2(wA2[32 + j],     h0, aA0);
            aB0 = dot2(wB2[32 + j],     h0, aB0);
            aA1 = dot2(wA2[32 + j + 1], h1, aA1);
            aB1 = dot2(wB2[32 + j + 1], h1, aB1);
        }

        const float xnext = xs[t + 1];               // prefetch (pad-safe)
        const float baseA = fmaf(xcur, wihA, biasA);
        const float baseB = fmaf(xcur, wihB, biasB);
        xcur = xnext;

        hnA = ftanh2(baseA + (aA0 + aA1));
        hnB = ftanh2(baseB + (aB0 + aB1));

        // ---- logits: 2 classes, reduced over 128 rows held in-lane.
        float c0 = fmaf(wf0A, hnA, wf0B * hnB);
        float c1 = fmaf(wf1A, hnA, wf1B * hnB);
        c0 = DPP_ADD(c0, 0xB1);  c1 = DPP_ADD(c1, 0xB1);   // xor1
        c0 = DPP_ADD(c0, 0x4E);  c1 = DPP_ADD(c1, 0x4E);   // xor2
        c0 = DPP_ADD(c0, 0x124); c1 = DPP_ADD(c1, 0x124);  // ror4 (row16)
        c0 = DPP_ADD(c0, 0x128); c1 = DPP_ADD(c1, 0x128);  // ror8 -> row16 sums
        float q0 = (bcast(c0, 0) + bcast(c0, 16)) + (bcast(c0, 32) + bcast(c0, 48));
        float q1 = (bcast(c1, 0) + bcast(c1, 16)) + (bcast(c1, 32) + bcast(c1, 48));

        if (l == 0) {
            *(f32x2*)(o + t * CC) = f32x2{q0 + bf0, q1 + bf1};
        }
    }
}

extern "C" void kernel_launch(void* const* d_in, const int* in_sizes, int n_in,
                              void* d_out, int out_size, void* d_ws, size_t ws_size,
                              hipStream_t stream) {
    const float* x    = (const float*)d_in[0];
    const float* W_ih = (const float*)d_in[1];
    const float* W_hh = (const float*)d_in[2];
    const float* b_ih = (const float*)d_in[3];
    const float* b_hh = (const float*)d_in[4];
    const float* W_fc = (const float*)d_in[5];
    const float* b_fc = (const float*)d_in[6];
    float* out = (float*)d_out;
    unsigned* wp = (unsigned*)d_ws;   // 32 KB: 8192 packed f16-pair dwords

    pack_w<<<32, 256, 0, stream>>>(W_hh, wp);
    rnn_kernel<<<BB, 64, 0, stream>>>(x, W_ih, wp, b_ih, b_hh, W_fc, b_fc, out);
}